// Round 2
// baseline (1389.700 us; speedup 1.0000x reference)
//
#include <hip/hip_runtime.h>

#define LSEQ 2048
#define HDIM 2048
#define NHEAD 16
#define DHEAD 128
#define N1 14336   // 3H + MLP
#define NC 10240   // H + MLP

typedef unsigned short u16;
typedef __attribute__((ext_vector_type(8))) short short8;
typedef __attribute__((ext_vector_type(4))) float f32x4;

#define ASYNC16(g, l) __builtin_amdgcn_global_load_lds( \
    (__attribute__((address_space(1))) void*)(g),        \
    (__attribute__((address_space(3))) void*)(l), 16, 0, 0)

__device__ __forceinline__ u16 f2bf(float f) {
  unsigned u = __builtin_bit_cast(unsigned, f);
  u += 0x7fffu + ((u >> 16) & 1u);
  return (u16)(u >> 16);
}
__device__ __forceinline__ u16 f2bf_trunc(float f) {   // for probs in [0,1]
  return (u16)(__builtin_bit_cast(unsigned, f) >> 16);
}
__device__ __forceinline__ float bf2f(u16 v) {
  unsigned u = ((unsigned)v) << 16;
  return __builtin_bit_cast(float, u);
}
__device__ __forceinline__ float silu_f(float x) { return x / (1.f + __expf(-x)); }
__device__ __forceinline__ float gelu_f(float x) {
  float u = 0.7978845608028654f * (x + 0.044715f * x * x * x);
  float e = __expf(2.f * u);
  float th = 1.f - 2.f / (e + 1.f);
  return 0.5f * x * (1.f + th);
}

// ---------------- mod = silu(vec) @ mod_w.T + mod_b ----------------
__global__ __launch_bounds__(256) void k_mod(const float* __restrict__ vec,
                                             const float* __restrict__ mod_w,
                                             const float* __restrict__ mod_b,
                                             float* __restrict__ modv) {
  int j = blockIdx.x, t = threadIdx.x;
  const float4* wr = (const float4*)(mod_w + (size_t)j * HDIM);
  const float4* vv = (const float4*)vec;
  float s0 = 0.f, s1 = 0.f;
#pragma unroll
  for (int i = 0; i < 2; i++) {
    int idx = t + i * 256;
    float4 w = wr[idx];
    float4 a = vv[idx];
    float4 c = vv[idx + 512];
    s0 += w.x*silu_f(a.x) + w.y*silu_f(a.y) + w.z*silu_f(a.z) + w.w*silu_f(a.w);
    s1 += w.x*silu_f(c.x) + w.y*silu_f(c.y) + w.z*silu_f(c.z) + w.w*silu_f(c.w);
  }
  int lane = t & 63, wid = t >> 6;
#pragma unroll
  for (int o = 32; o; o >>= 1) { s0 += __shfl_down(s0, o, 64); s1 += __shfl_down(s1, o, 64); }
  __shared__ float red[8];
  if (!lane) { red[wid] = s0; red[4 + wid] = s1; }
  __syncthreads();
  if (!t) {
    float b_ = mod_b[j];
    modv[j] = red[0]+red[1]+red[2]+red[3] + b_;
    modv[3*HDIM + j] = red[4]+red[5]+red[6]+red[7] + b_;
  }
}

// ---------------- x_mod = (1+scale)*LN(x) + shift, bf16 ----------------
__global__ __launch_bounds__(256) void k_ln(const float* __restrict__ x,
                                            const float* __restrict__ modv,
                                            u16* __restrict__ xmod) {
  int row = blockIdx.x, t = threadIdx.x;
  int b = row >> 11;
  const float4* xr = (const float4*)(x + (size_t)row * HDIM);
  float4 v0 = xr[t], v1 = xr[t + 256];
  float sum = v0.x+v0.y+v0.z+v0.w + v1.x+v1.y+v1.z+v1.w;
  float sq  = v0.x*v0.x+v0.y*v0.y+v0.z*v0.z+v0.w*v0.w
            + v1.x*v1.x+v1.y*v1.y+v1.z*v1.z+v1.w*v1.w;
  int lane = t & 63, wid = t >> 6;
#pragma unroll
  for (int o = 32; o; o >>= 1) { sum += __shfl_down(sum, o, 64); sq += __shfl_down(sq, o, 64); }
  __shared__ float red[8];
  if (!lane) { red[wid] = sum; red[4+wid] = sq; }
  __syncthreads();
  sum = red[0]+red[1]+red[2]+red[3];
  sq  = red[4]+red[5]+red[6]+red[7];
  float mu = sum * (1.f/HDIM);
  float rstd = rsqrtf(sq * (1.f/HDIM) - mu*mu + 1e-6f);
  const float* mb = modv + b * (3*HDIM);
  u16* orow = xmod + (size_t)row * HDIM;
  float vv[8] = {v0.x,v0.y,v0.z,v0.w,v1.x,v1.y,v1.z,v1.w};
#pragma unroll
  for (int half = 0; half < 2; half++) {
    int h0 = (t + half*256) * 4;
    ushort4 o4;
    float e0 = (1.f + mb[HDIM + h0+0]) * ((vv[half*4+0]-mu)*rstd) + mb[h0+0];
    float e1 = (1.f + mb[HDIM + h0+1]) * ((vv[half*4+1]-mu)*rstd) + mb[h0+1];
    float e2 = (1.f + mb[HDIM + h0+2]) * ((vv[half*4+2]-mu)*rstd) + mb[h0+2];
    float e3 = (1.f + mb[HDIM + h0+3]) * ((vv[half*4+3]-mu)*rstd) + mb[h0+3];
    o4.x = f2bf(e0); o4.y = f2bf(e1); o4.z = f2bf(e2); o4.w = f2bf(e3);
    *(ushort4*)(orow + h0) = o4;
  }
}

// ---------------- f32 -> bf16 weight convert ----------------
__global__ __launch_bounds__(256) void k_cvt(const float4* __restrict__ src,
                                             ushort4* __restrict__ dst, int n4) {
  int i = blockIdx.x * 256 + threadIdx.x;
  int stride = gridDim.x * 256;
  for (; i < n4; i += stride) {
    float4 v = src[i];
    ushort4 o;
    o.x = f2bf(v.x); o.y = f2bf(v.y); o.z = f2bf(v.z); o.w = f2bf(v.w);
    dst[i] = o;
  }
}

// ---------------- GEMM1: h = xmod @ W1^T + b1 ; split qkv / gelu(mlp) ----------------
// 256x256 tile, BK=64, 8 waves (2x4). v2 schedule: single barrier per phase,
// 2 counted vmcnt waits per K-tile (leads 3-4 phases), even frag reads 8/8/8/0
// with cross-phase feeding (a0 of tile t+1 read during P2 of tile t).
// Staging units per K-tile (2 ASYNC16/wave each):
//   U0 = A rows {0-63,128-191}   (Q00/Q01 rows)   staged at P2 of t-1... wait: U0_{t+2} @ P2_t
//   U1 = A rows {64-127,192-255} (Q11/Q10 rows)   U3_{t+1},U1_{t+1} @ P0_t
//   U2 = B cols qn=0 rows        U2_{t+2} @ P3_t
//   U3 = B cols qn=1 rows
// Wait ledger (steady state, queue entering P0_t = [U0_{t+1},U2_{t+1}]):
//   P0: +U3,U1_{t+1} -> 8 outstanding, no wait
//   P1: vmcnt(6) drains U0_{t+1} (3-phase lead), read by P2's a0' frag loads
//   P2: +U0_{t+2} -> 8, no wait
//   P3: +U2_{t+2} -> 10, vmcnt(4) drains U2/U3/U1_{t+1} (3-4 phase leads)
#define FENCE asm volatile("" ::: "memory")
#define BARRIER { FENCE; __builtin_amdgcn_s_barrier(); FENCE; }
#define WAITVM(n) asm volatile("s_waitcnt vmcnt(" #n ")" ::: "memory")

#define ABUF(bufv) (S + (bufv)*16384)
#define BBUF(bufv) (S + 32768 + (bufv)*16384)

#define STG_A(bufv, rbase, kk) do { \
    int r_ = (rbase) + wave * 8; \
    ASYNC16(Ab + (size_t)(r_ + lr) * K + (kk) + sg * 8, ABUF(bufv) + r_ * 64); \
  } while (0)
#define STG_B(bufv, rbase, kk) do { \
    int r_ = (rbase) + (wave >> 2) * 64 + (wave & 3) * 8; \
    ASYNC16(Bb + (size_t)(r_ + lr) * K + (kk) + sg * 8, BBUF(bufv) + r_ * 64); \
  } while (0)
#define STG_U0(bufv, kk) { STG_A(bufv, 0, kk);   STG_A(bufv, 128, kk); }
#define STG_U1(bufv, kk) { STG_A(bufv, 64, kk);  STG_A(bufv, 192, kk); }
#define STG_U2(bufv, kk) { STG_B(bufv, 0, kk);   STG_B(bufv, 128, kk); }
#define STG_U3(bufv, kk) { STG_B(bufv, 32, kk);  STG_B(bufv, 160, kk); }

#define LDS_A(dst, qmv, bufv) do { \
    const u16* p_ = ABUF(bufv); \
    _Pragma("unroll") for (int mt = 0; mt < 4; mt++) { \
      int row_ = wm*128 + (qmv)*64 + mt*16 + fm; \
      _Pragma("unroll") for (int ks = 0; ks < 2; ks++) \
        dst[mt][ks] = *(const short8*)(p_ + row_*64 + (((ks*4 + fq) ^ (fm & 7)) * 8)); \
    } } while (0)
#define LDS_Bv(dst, qnv, bufv) do { \
    const u16* p_ = BBUF(bufv); \
    _Pragma("unroll") for (int nt = 0; nt < 2; nt++) { \
      int row_ = wn*64 + (qnv)*32 + nt*16 + fm; \
      _Pragma("unroll") for (int ks = 0; ks < 2; ks++) \
        dst[nt][ks] = *(const short8*)(p_ + row_*64 + (((ks*4 + fq) ^ (fm & 7)) * 8)); \
    } } while (0)

#define MMQ(qmv, qnv, Aa, Bv) do { \
    __builtin_amdgcn_s_setprio(1); \
    _Pragma("unroll") for (int mt = 0; mt < 4; mt++) \
    _Pragma("unroll") for (int nt = 0; nt < 2; nt++) \
    _Pragma("unroll") for (int ks = 0; ks < 2; ks++) \
      acc[(qmv)*4 + mt][(qnv)*2 + nt] = __builtin_amdgcn_mfma_f32_16x16x32_bf16( \
          Aa[mt][ks], Bv[nt][ks], acc[(qmv)*4 + mt][(qnv)*2 + nt], 0, 0, 0); \
    __builtin_amdgcn_s_setprio(0); } while (0)

// One K-tile: 4 phases, 1 barrier each. Flags gate tail behavior.
#define GTILE(bufv, k1, k2, S01, RDA0, S2, S3, W1, W3) do { \
    /* P0: b-frags for Q00/Q01/Q10; stage U3/U1 of t+1 */ \
    LDS_Bv(b0r, 0, bufv); \
    LDS_Bv(b1r, 1, bufv); \
    if (S01) { STG_U3((bufv)^1, k1); STG_U1((bufv)^1, k1); } \
    BARRIER; \
    MMQ(0, 0, areg0, b0r); \
    /* P1: a1 frags for Q11/Q10 */ \
    LDS_A(areg1, 1, bufv); \
    W1; \
    BARRIER; \
    MMQ(0, 1, areg0, b1r); \
    /* P2: a0 frags of NEXT tile; stage U0 of t+2 */ \
    if (RDA0) LDS_A(areg0, 0, (bufv)^1); \
    if (S2) STG_U0(bufv, k2); \
    BARRIER; \
    MMQ(1, 1, areg1, b1r); \
    /* P3: stage U2 of t+2 */ \
    if (S3) STG_U2(bufv, k2); \
    W3; \
    BARRIER; \
    MMQ(1, 0, areg1, b0r); \
  } while (0)

__global__ __launch_bounds__(512, 2) void k_gemm1(const u16* __restrict__ A,
                                                  const u16* __restrict__ Bw,
                                                  const float* __restrict__ bias,
                                                  u16* __restrict__ qkv,
                                                  u16* __restrict__ cat) {
  const int K = HDIM;
  // XCD-bijective swizzle: 896 blocks, 896 % 8 == 0 -> 112 per XCD
  int orig = blockIdx.x;
  int bid = (orig & 7) * 112 + (orig >> 3);
  int bm = bid & 15, bn = bid >> 4;      // bm fastest within an XCD chunk
  int t = threadIdx.x, wave = t >> 6, lane = t & 63;
  int wm = wave >> 2, wn = wave & 3;     // 2x4 wave grid, wave tile 128x64
  int fm = lane & 15, fq = lane >> 4;
  int lr = lane >> 3, lg = lane & 7;     // staging: row-in-band / granule
  int sg = lg ^ lr;                      // pre-swizzled global source granule

  __shared__ u16 S[65536];               // 128 KiB: A dbuf + B dbuf

  const u16* Ab = A + (size_t)bm * 256 * K;
  const u16* Bb = Bw + (size_t)bn * 256 * K;

  const f32x4 fzero = {0.f, 0.f, 0.f, 0.f};
  f32x4 acc[8][4];
#pragma unroll
  for (int i = 0; i < 8; i++)
#pragma unroll
    for (int j2 = 0; j2 < 4; j2++) acc[i][j2] = fzero;
  short8 areg0[4][2], areg1[4][2], b0r[2][2], b1r[2][2];

  // prologue: tile0 all units, then U0_1 (P2_-1 slot) and U2_1 (P3_-1 slot)
  STG_U0(0, 0); STG_U2(0, 0); STG_U3(0, 0); STG_U1(0, 0);
  STG_U0(1, 64);
  STG_U2(1, 64);
  WAITVM(4);                             // tile0 landed; queue = [U0_1, U2_1]
  BARRIER;
  LDS_A(areg0, 0, 0);                    // a0_0 (the P2_{-1} frag read)

  for (int t2 = 0; t2 < 15; ++t2) {      // tiles 0..29
    int k0 = t2 * 128;
    GTILE(0, k0+64,  k0+128, 1, 1, 1, 1, WAITVM(6), WAITVM(4));
    GTILE(1, k0+128, k0+192, 1, 1, 1, 1, WAITVM(6), WAITVM(4));
  }
  // tile 30: stage U3/U1 of 31 only; drain to 0 at P3
  GTILE(0, 31*64, 0, 1, 1, 0, 0, WAITVM(6), WAITVM(0));
  // tile 31: no stages, no waits, no next-tile reads
  GTILE(1, 0,     0, 0, 0, 0, 0, ((void)0), ((void)0));

  // ---- epilogue: bias (+gelu for mlp), LDS restage, coalesced 16B stores ----
  bool ismlp = (bn >= 24);               // 3H = 6144 = 24*256, uniform per block
  const int EP = 264;                    // padded pitch
  u16* Sep = S;                          // reuse LDS (33792 u16 <= 65536)
#pragma unroll
  for (int half = 0; half < 2; half++) {
    BARRIER;
    if (wm == half) {
#pragma unroll
      for (int j = 0; j < 4; j++) {
        int col_l = wn*64 + j*16 + fm;
        float bv = bias[bn*256 + col_l];
#pragma unroll
        for (int i = 0; i < 8; i++) {
#pragma unroll
          for (int rr = 0; rr < 4; rr++) {
            float v = acc[i][j][rr] + bv;
            if (ismlp) v = gelu_f(v);
            Sep[(i*16 + fq*4 + rr)*EP + col_l] = f2bf(v);
          }
        }
      }
    }
    BARRIER;
    int cg = (t & 31) * 8;
    int r0 = t >> 5;
#pragma unroll
    for (int p = 0; p < 8; p++) {
      int r_l = p*16 + r0;
      short8 v = *(const short8*)&Sep[r_l*EP + cg];
      int row_g = bm*256 + half*128 + r_l;
      if (!ismlp)
        *(short8*)(qkv + (size_t)row_g*(3*HDIM) + bn*256 + cg) = v;
      else
        *(short8*)(cat + (size_t)row_g*NC + HDIM + (bn-24)*256 + cg) = v;
    }
  }
}

// ---------------- GEMM2: out = x + gate*(cat @ W2^T + b2) ----------------
__global__ __launch_bounds__(256, 2) void k_gemm2(const u16* __restrict__ A,
                                                  const u16* __restrict__ Bw,
                                                  const float* __restrict__ bias,
                                                  const float* __restrict__ xres,
                                                  const float* __restrict__ modv,
                                                  float* __restrict__ out) {
  const int K = NC;
  int bid = blockIdx.x;
  int bm = bid & 31, bn = bid >> 5;     // bm fastest
  int t = threadIdx.x, wave = t >> 6, lane = t & 63;
  int wm = wave >> 1, wn = wave & 1;
  __shared__ u16 As[2*128*32];
  __shared__ u16 Bs[2*128*32];
  const f32x4 fzero = {0.f, 0.f, 0.f, 0.f};
  f32x4 acc[4][4];
#pragma unroll
  for (int i = 0; i < 4; i++)
#pragma unroll
    for (int j2 = 0; j2 < 4; j2++) acc[i][j2] = fzero;
  const u16* Ab = A + (size_t)bm * 128 * K;
  const u16* Bb = Bw + (size_t)bn * 128 * K;
  int r4 = lane >> 2, c4 = lane & 3;
  int fm = lane & 15, fk = (lane >> 4) * 8;
  for (int k0 = 0; k0 < K; k0 += 64) {
#pragma unroll
    for (int i = 0; i < 2; i++) {
      int row = wave*32 + i*16;
      const u16* ar = Ab + (size_t)(row + r4)*K + k0 + c4*8;
      const u16* br = Bb + (size_t)(row + r4)*K + k0 + c4*8;
      ASYNC16(ar,      &As[row*32]);
      ASYNC16(ar + 32, &As[4096 + row*32]);
      ASYNC16(br,      &Bs[row*32]);
      ASYNC16(br + 32, &Bs[4096 + row*32]);
    }
    __syncthreads();
#pragma unroll
    for (int p = 0; p < 2; p++) {
      const u16* Ap = &As[p*4096];
      const u16* Bp = &Bs[p*4096];
      short8 af[4], bfr[4];
#pragma unroll
      for (int mt = 0; mt < 4; mt++)
        af[mt] = *(const short8*)&Ap[(wm*64 + mt*16 + fm)*32 + fk];
#pragma unroll
      for (int nt = 0; nt < 4; nt++)
        bfr[nt] = *(const short8*)&Bp[(wn*64 + nt*16 + fm)*32 + fk];
#pragma unroll
      for (int mt = 0; mt < 4; mt++)
#pragma unroll
        for (int nt = 0; nt < 4; nt++)
          acc[mt][nt] = __builtin_amdgcn_mfma_f32_16x16x32_bf16(af[mt], bfr[nt], acc[mt][nt], 0, 0, 0);
    }
    __syncthreads();
  }
  int rbase = bm*128 + wm*64;
  int cbase = bn*128 + wn*64;
  int b = (bm*128) >> 11;
#pragma unroll
  for (int nt = 0; nt < 4; nt++) {
    int col = cbase + nt*16 + fm;
    float bv = bias[col];
    float g = modv[b*(3*HDIM) + 2*HDIM + col];
#pragma unroll
    for (int mt = 0; mt < 4; mt++) {
#pragma unroll
      for (int rr = 0; rr < 4; rr++) {
        int row = rbase + mt*16 + (lane>>4)*4 + rr;
        size_t idx = (size_t)row*HDIM + col;
        out[idx] = xres[idx] + g * (acc[mt][nt][rr] + bv);
      }
    }
  }
}

// ---------------- q,k: rmsnorm + rope -> Q,K (b,h,l,d) bf16 ----------------
__global__ __launch_bounds__(256) void k_qk(const u16* __restrict__ qkv,
                                            const float* __restrict__ pe,
                                            const float* __restrict__ q_scale,
                                            const float* __restrict__ k_scale,
                                            u16* __restrict__ Q, u16* __restrict__ Ko) {
  int bid = blockIdx.x;                  // b*L + l
  int l = bid & (LSEQ-1);
  int b = bid >> 11;
  int t = threadIdx.x;
  int h = t >> 4;
  int dc = (t & 15) * 8;
  const u16* base = qkv + (size_t)bid * (3*HDIM);
  short8 q8 = *(const short8*)(base + h*DHEAD + dc);
  short8 k8 = *(const short8*)(base + HDIM + h*DHEAD + dc);
  float qf[8], kf[8];
  float sq = 0.f, sk = 0.f;
#pragma unroll
  for (int i = 0; i < 8; i++) {
    qf[i] = bf2f((u16)q8[i]); kf[i] = bf2f((u16)k8[i]);
    sq += qf[i]*qf[i]; sk += kf[i]*kf[i];
  }
#pragma unroll
  for (int m = 1; m < 16; m <<= 1) { sq += __shfl_xor(sq, m, 64); sk += __shfl_xor(sk, m, 64); }
  float rq = rsqrtf(sq * (1.f/DHEAD) + 1e-6f);
  float rk = rsqrtf(sk * (1.f/DHEAD) + 1e-6f);
  float4 qs0 = *(const float4*)(q_scale + dc), qs1 = *(const float4*)(q_scale + dc + 4);
  float4 ks0 = *(const float4*)(k_scale + dc), ks1 = *(const float4*)(k_scale + dc + 4);
  float qsc[8] = {qs0.x,qs0.y,qs0.z,qs0.w,qs1.x,qs1.y,qs1.z,qs1.w};
  float ksc[8] = {ks0.x,ks0.y,ks0.z,ks0.w,ks1.x,ks1.y,ks1.z,ks1.w};
  float qn[8], kn[8];
#pragma unroll
  for (int i = 0; i < 8; i++) { qn[i] = qf[i]*rq*qsc[i]; kn[i] = kf[i]*rk*ksc[i]; }
  const float4* pe4 = (const float4*)pe + ((size_t)bid*64 + (dc >> 1));
  short8 qo, ko;
#pragma unroll
  for (int pi = 0; pi < 4; pi++) {
    float4 pp = pe4[pi];
    float q0 = pp.x*qn[2*pi] + pp.y*qn[2*pi+1];
    float q1 = pp.z*qn[2*pi] + pp.w*qn[2*pi+1];
    float k0 = pp.x*kn[2*pi] + pp.y*kn[2*pi+1];
    float k1 = pp.z*kn[2*pi] + pp.w*kn[2*pi+1];
    qo[2*pi] = (short)f2bf(q0); qo[2*pi+1] = (short)f2bf(q1);
    ko[2*pi] = (short)f2bf(k0); ko[2*pi+1] = (short)f2bf(k1);
  }
  size_t oidx = (((size_t)(b*NHEAD + h))*LSEQ + l)*DHEAD + dc;
  *(short8*)(Q + oidx) = qo;
  *(short8*)(Ko + oidx) = ko;
}

// ---------------- V transpose: qkv v-part -> Vt (b,h,d,l) bf16 ----------------
__global__ __launch_bounds__(256) void k_vt(const u16* __restrict__ qkv, u16* __restrict__ Vt) {
  int bid = blockIdx.x;
  int lt = bid & 31, h = (bid >> 5) & 15, b = bid >> 9;
  __shared__ u16 tile[64][132];
  int t = threadIdx.x;
#pragma unroll
  for (int it = 0; it < 8; it++) {
    int idx = it*1024 + t*4;
    int li = idx >> 7, di = idx & 127;
    const u16* src = qkv + ((size_t)(b*LSEQ + lt*64 + li))*(3*HDIM) + 2*HDIM + h*DHEAD + di;
    ushort4 v = *(const ushort4*)src;
    *(ushort4*)&tile[li][di] = v;
  }
  __syncthreads();
  u16* dst = Vt + ((size_t)(b*NHEAD + h))*DHEAD*LSEQ + lt*64;
#pragma unroll
  for (int it = 0; it < 32; it++) {
    int idx = it*256 + t;
    int lo = idx & 63, dd = idx >> 6;
    dst[(size_t)dd*LSEQ + lo] = tile[lo][dd];
  }
}

// ---------------- flash attention: no-max softmax (rmsnorm bounds logits) ----------------
// |q|=|k|=sqrt(128)*O(1) after rmsnorm => |logit| <~ 34; exp2 range-safe in fp32.
#define SC2 0.12753329583f   // (1/sqrt(128)) * log2(e)
__global__ __launch_bounds__(256, 2) void k_attn(const u16* __restrict__ Q,
                                                 const u16* __restrict__ Kc,
                                                 const u16* __restrict__ Vt,
                                                 u16* __restrict__ cat) {
  __shared__ u16 Ks[2*64*128];   // 32 KB dbuf
  __shared__ u16 Vs[2*128*64];   // 32 KB dbuf
  __shared__ u16 Ps[64*88];      // per-wave private rows
  int bid = blockIdx.x;
  int bh = bid & 31, qt = bid >> 5;
  int h = bh & 15, b = bh >> 4;
  int t = threadIdx.x, wave = t >> 6, lane = t & 63;
  int fm = lane & 15, fq = lane >> 4;
  int r8 = lane >> 3, c8 = lane & 7;
  const u16* Qg = Q  + (((size_t)(b*NHEAD + h))*LSEQ + qt*64) * DHEAD;
  const u16* Kg = Kc + ((size_t)(b*NHEAD + h))*LSEQ * DHEAD;
  const u16* Vg = Vt + ((size_t)(b*NHEAD + h))*DHEAD*LSEQ;
  short8 aq[4];
#pragma unroll
  for (int ks = 0; ks < 4; ks++)
    aq[ks] = *(const short8*)(Qg + (size_t)(wave*16 + fm)*DHEAD + ks*32 + fq*8);
#pragma unroll
  for (int i = 0; i < 4; i++) {
    int row = wave*16 + i*4;
    ASYNC16(Kg + (size_t)(row + fq)*DHEAD + fm*8, &Ks[row*DHEAD]);
    int vrow = wave*32 + i*8;
    ASYNC16(Vg + (size_t)(vrow + r8)*LSEQ + c8*8, &Vs[vrow*64]);
  }
  const f32x4 fzero = {0.f, 0.f, 0.f, 0.f};
  f32x4 o[8];
#pragma unroll
  for (int i = 0; i < 8; i++) o[i] = fzero;
  float lsum[4] = {0.f, 0.f, 0.f, 0.f};
  for (int kt = 0; kt < 32; kt++) {
    int cur = kt & 1;
    __syncthreads();   // drains prev-iter staging (issued a full iter ago)
    if (kt < 31) {
      int off = (cur ^ 1) * 8192;
      const u16* Kt_ = Kg + (size_t)(kt+1)*64*DHEAD;
      const u16* Vt_ = Vg + (kt+1)*64;
#pragma unroll
      for (int i = 0; i < 4; i++) {
        int row = wave*16 + i*4;
        ASYNC16(Kt_ + (size_t)(row + fq)*DHEAD + fm*8, &Ks[off + row*DHEAD]);
        int vrow = wave*32 + i*8;
        ASYNC16(Vt_ + (size_t)(vrow + r8)*LSEQ + c8*8, &Vs[off + vrow*64]);
      }
    }
    const u16* Kb = &Ks[cur*8192];
    const u16* Vb = &Vs[cur*8192];
    f32x4 s[4];
#pragma unroll
    for (int nt = 0; nt < 4; nt++) s[nt] = fzero;
#pragma unroll
    for (int ks = 0; ks < 4; ks++) {
#pragma unroll
      for (int nt = 0; nt < 4; nt++) {
        short8 bk = *(const short8*)&Kb[(nt*16 + fm)*DHEAD + ks*32 + fq*8];
        s[nt] = __builtin_amdgcn_mfma_f32_16x16x32_bf16(aq[ks], bk, s[nt], 0, 0, 0);
      }
    }
    // p = 2^(s*SC2); accumulate per-lane row sums, no max / no rescale
#pragma unroll
    for (int nt = 0; nt < 4; nt++)
#pragma unroll
      for (int r = 0; r < 4; r++) {
        float p = exp2f(s[nt][r] * SC2);
        s[nt][r] = p;
        lsum[r] += p;
      }
#pragma unroll
    for (int nt = 0; nt < 4; nt++)
#pragma unroll
      for (int r = 0; r < 4; r++)
        Ps[(wave*16 + fq*4 + r)*88 + nt*16 + fm] = f2bf_trunc(s[nt][r]);
    asm volatile("s_waitcnt lgkmcnt(0)" ::: "memory");
#pragma unroll
    for (int ks2 = 0; ks2 < 2; ks2++) {
      short8 ap = *(const short8*)&Ps[(wave*16 + fm)*88 + ks2*32 + fq*8];
#pragma unroll
      for (int nt = 0; nt < 8; nt++) {
        short8 bv = *(const short8*)&Vb[(nt*16 + fm)*64 + ks2*32 + fq*8];
        o[nt] = __builtin_amdgcn_mfma_f32_16x16x32_bf16(ap, bv, o[nt], 0, 0, 0);
      }
    }
  }
  // single final reduction of row sums over the 16 column-lanes
#pragma unroll
  for (int r = 0; r < 4; r++) {
#pragma unroll
    for (int o2 = 8; o2 >= 1; o2 >>= 1) lsum[r] += __shfl_xor(lsum[r], o2, 64);
  }
#pragma unroll
  for (int nt = 0; nt < 8; nt++) {
#pragma unroll
    for (int r = 0; r < 4; r++) {
      int l = qt*64 + wave*16 + fq*4 + r;
      int d = nt*16 + fm;
      float v = o[nt][r] / lsum[r];
      cat[((size_t)(b*LSEQ + l))*NC + h*DHEAD + d] = f2bf(v);
    }
  }
}

// ---------------- launch ----------------
extern "C" void kernel_launch(void* const* d_in, const int* in_sizes, int n_in,
                              void* d_out, int out_size, void* d_ws, size_t ws_size,
                              hipStream_t stream) {
  const float* x       = (const float*)d_in[0];
  const float* vec     = (const float*)d_in[1];
  const float* pe      = (const float*)d_in[2];
  const float* mod_w   = (const float*)d_in[3];
  const float* mod_b   = (const float*)d_in[4];
  const float* lin1_w  = (const float*)d_in[5];
  const float* lin1_b  = (const float*)d_in[6];
  const float* lin2_w  = (const float*)d_in[7];
  const float* lin2_b  = (const float*)d_in[8];
  const float* q_scale = (const float*)d_in[9];
  const float* k_scale = (const float*)d_in[10];
  char* ws = (char*)d_ws;

  // workspace layout, high-water ~210 MB
  float* modv = (float*)(ws + 0);                 //  48 KB
  u16* xmod  = (u16*)(ws + 65536ULL);             //  16.8 MB
  u16* qkv   = (u16*)(ws + 16842752ULL);          //  50.3 MB (dead after qk/vt)
  u16* w2    = (u16*)(ws + 16842752ULL);          //  aliases qkv (written after qk/vt)
  u16* cat   = (u16*)(ws + 67174400ULL);          //  83.9 MB
  u16* w1    = (u16*)(ws + 151060480ULL);         //  58.7 MB (dead after GEMM1)
  u16* Qb    = (u16*)(ws + 151060480ULL);         //  aliases w1
  u16* Kb    = (u16*)(ws + 167837696ULL);
  u16* Vtb   = (u16*)(ws + 184614912ULL);         //  end at ~201.4 MB

  k_mod<<<dim3(3*HDIM), dim3(256), 0, stream>>>(vec, mod_w, mod_b, modv);
  k_cvt<<<dim3(4096), dim3(256), 0, stream>>>((const float4*)lin1_w, (ushort4*)w1, (N1*HDIM)/4);
  k_ln<<<dim3(4096), dim3(256), 0, stream>>>(x, modv, xmod);
  k_gemm1<<<dim3(896), dim3(512), 0, stream>>>(xmod, w1, lin1_b, qkv, cat);
  k_qk<<<dim3(4096), dim3(256), 0, stream>>>(qkv, pe, q_scale, k_scale, Qb, Kb);
  k_vt<<<dim3(1024), dim3(256), 0, stream>>>(qkv, Vtb);
  k_cvt<<<dim3(4096), dim3(256), 0, stream>>>((const float4*)lin2_w, (ushort4*)w2, (HDIM*NC)/4);
  k_attn<<<dim3(1024), dim3(256), 0, stream>>>(Qb, Kb, Vtb, cat);
  k_gemm2<<<dim3(32*16), dim3(256), 0, stream>>>(cat, w2, lin2_b, x, modv, (float*)d_out);
}

// Round 4
// 1022.499 us; speedup vs baseline: 1.3591x; 1.3591x over previous
//
#include <hip/hip_runtime.h>

#define LSEQ 2048
#define HDIM 2048
#define NHEAD 16
#define DHEAD 128
#define N1 14336   // 3H + MLP
#define NC 10240   // H + MLP

typedef unsigned short u16;
typedef __attribute__((ext_vector_type(8))) short short8;
typedef __attribute__((ext_vector_type(4))) float f32x4;

#define ASYNC16(g, l) __builtin_amdgcn_global_load_lds( \
    (__attribute__((address_space(1))) void*)(g),        \
    (__attribute__((address_space(3))) void*)(l), 16, 0, 0)

__device__ __forceinline__ u16 f2bf(float f) {
  unsigned u = __builtin_bit_cast(unsigned, f);
  u += 0x7fffu + ((u >> 16) & 1u);
  return (u16)(u >> 16);
}
__device__ __forceinline__ u16 f2bf_trunc(float f) {   // for probs in [0,1]
  return (u16)(__builtin_bit_cast(unsigned, f) >> 16);
}
__device__ __forceinline__ float bf2f(u16 v) {
  unsigned u = ((unsigned)v) << 16;
  return __builtin_bit_cast(float, u);
}
__device__ __forceinline__ float silu_f(float x) { return x / (1.f + __expf(-x)); }
__device__ __forceinline__ float gelu_f(float x) {
  float u = 0.7978845608028654f * (x + 0.044715f * x * x * x);
  float e = __expf(2.f * u);
  float th = 1.f - 2.f / (e + 1.f);
  return 0.5f * x * (1.f + th);
}

// ---------------- mod = silu(vec) @ mod_w.T + mod_b ----------------
__global__ __launch_bounds__(256) void k_mod(const float* __restrict__ vec,
                                             const float* __restrict__ mod_w,
                                             const float* __restrict__ mod_b,
                                             float* __restrict__ modv) {
  int j = blockIdx.x, t = threadIdx.x;
  const float4* wr = (const float4*)(mod_w + (size_t)j * HDIM);
  const float4* vv = (const float4*)vec;
  float s0 = 0.f, s1 = 0.f;
#pragma unroll
  for (int i = 0; i < 2; i++) {
    int idx = t + i * 256;
    float4 w = wr[idx];
    float4 a = vv[idx];
    float4 c = vv[idx + 512];
    s0 += w.x*silu_f(a.x) + w.y*silu_f(a.y) + w.z*silu_f(a.z) + w.w*silu_f(a.w);
    s1 += w.x*silu_f(c.x) + w.y*silu_f(c.y) + w.z*silu_f(c.z) + w.w*silu_f(c.w);
  }
  int lane = t & 63, wid = t >> 6;
#pragma unroll
  for (int o = 32; o; o >>= 1) { s0 += __shfl_down(s0, o, 64); s1 += __shfl_down(s1, o, 64); }
  __shared__ float red[8];
  if (!lane) { red[wid] = s0; red[4 + wid] = s1; }
  __syncthreads();
  if (!t) {
    float b_ = mod_b[j];
    modv[j] = red[0]+red[1]+red[2]+red[3] + b_;
    modv[3*HDIM + j] = red[4]+red[5]+red[6]+red[7] + b_;
  }
}

// ---------------- x_mod = (1+scale)*LN(x) + shift, bf16 ----------------
__global__ __launch_bounds__(256) void k_ln(const float* __restrict__ x,
                                            const float* __restrict__ modv,
                                            u16* __restrict__ xmod) {
  int row = blockIdx.x, t = threadIdx.x;
  int b = row >> 11;
  const float4* xr = (const float4*)(x + (size_t)row * HDIM);
  float4 v0 = xr[t], v1 = xr[t + 256];
  float sum = v0.x+v0.y+v0.z+v0.w + v1.x+v1.y+v1.z+v1.w;
  float sq  = v0.x*v0.x+v0.y*v0.y+v0.z*v0.z+v0.w*v0.w
            + v1.x*v1.x+v1.y*v1.y+v1.z*v1.z+v1.w*v1.w;
  int lane = t & 63, wid = t >> 6;
#pragma unroll
  for (int o = 32; o; o >>= 1) { sum += __shfl_down(sum, o, 64); sq += __shfl_down(sq, o, 64); }
  __shared__ float red[8];
  if (!lane) { red[wid] = sum; red[4+wid] = sq; }
  __syncthreads();
  sum = red[0]+red[1]+red[2]+red[3];
  sq  = red[4]+red[5]+red[6]+red[7];
  float mu = sum * (1.f/HDIM);
  float rstd = rsqrtf(sq * (1.f/HDIM) - mu*mu + 1e-6f);
  const float* mb = modv + b * (3*HDIM);
  u16* orow = xmod + (size_t)row * HDIM;
  float vv[8] = {v0.x,v0.y,v0.z,v0.w,v1.x,v1.y,v1.z,v1.w};
#pragma unroll
  for (int half = 0; half < 2; half++) {
    int h0 = (t + half*256) * 4;
    ushort4 o4;
    float e0 = (1.f + mb[HDIM + h0+0]) * ((vv[half*4+0]-mu)*rstd) + mb[h0+0];
    float e1 = (1.f + mb[HDIM + h0+1]) * ((vv[half*4+1]-mu)*rstd) + mb[h0+1];
    float e2 = (1.f + mb[HDIM + h0+2]) * ((vv[half*4+2]-mu)*rstd) + mb[h0+2];
    float e3 = (1.f + mb[HDIM + h0+3]) * ((vv[half*4+3]-mu)*rstd) + mb[h0+3];
    o4.x = f2bf(e0); o4.y = f2bf(e1); o4.z = f2bf(e2); o4.w = f2bf(e3);
    *(ushort4*)(orow + h0) = o4;
  }
}

// ---------------- f32 -> bf16 weight convert ----------------
__global__ __launch_bounds__(256) void k_cvt(const float4* __restrict__ src,
                                             ushort4* __restrict__ dst, int n4) {
  int i = blockIdx.x * 256 + threadIdx.x;
  int stride = gridDim.x * 256;
  for (; i < n4; i += stride) {
    float4 v = src[i];
    ushort4 o;
    o.x = f2bf(v.x); o.y = f2bf(v.y); o.z = f2bf(v.z); o.w = f2bf(v.w);
    dst[i] = o;
  }
}

// ---------------- GEMM1: h = xmod @ W1^T + b1 ; split qkv / gelu(mlp) ----------------
// 256x256 tile, BK=64, 8 waves (2x4). v3 schedule:
//  - r1's register discipline: one a[4][2] reused per qm half, b0r/b1r per tile
//    (64 frag VGPRs + 128 acc, no spill)
//  - r1's 2-barrier phase-lock (keeps blocks in lockstep -> L2 locality)
//  - r2's deep staging: P0_t:U3_{t+1}  P1_t:U1_{t+1}  P2_t:U0_{t+2}  P3_t:U2_{t+2}
//  - 3 counted waits/tile, vmcnt(8), leads 4-5 phases.
// Ledger invariant: entering P0_t, per-wave outstanding = [U3_t,U1_t,U0_{t+1},U2_{t+1}] = 8.
//   P0: +U3_{t+1}->10, vmcnt(8) drains U3_t   (read P1_t)
//   P1: +U1_{t+1}->10, vmcnt(8) drains U1_t   (read P2_t)
//   P2: +U0_{t+2}->10, no wait
//   P3: +U2_{t+2}->12, vmcnt(8) drains U0/U2_{t+1} (read P0_{t+1})
// Tail: t30 skips P2/P3 stages (P3 wait vmcnt(4)); t31 no stages, waits 2/0.
#define FENCE asm volatile("" ::: "memory")
#define BARRIER { FENCE; __builtin_amdgcn_s_barrier(); FENCE; }
#define WAITVM(n) asm volatile("s_waitcnt vmcnt(" #n ")" ::: "memory")

#define ABUF(bufv) (S + (bufv)*16384)
#define BBUF(bufv) (S + 32768 + (bufv)*16384)

#define STG_A(bufv, rbase, kk) do { \
    int r_ = (rbase) + wave * 8; \
    ASYNC16(Ab + (size_t)(r_ + lr) * K + (kk) + sg * 8, ABUF(bufv) + r_ * 64); \
  } while (0)
#define STG_B(bufv, rbase, kk) do { \
    int r_ = (rbase) + (wave >> 2) * 64 + (wave & 3) * 8; \
    ASYNC16(Bb + (size_t)(r_ + lr) * K + (kk) + sg * 8, BBUF(bufv) + r_ * 64); \
  } while (0)
#define STG_U0(bufv, kk) { STG_A(bufv, 0, kk);   STG_A(bufv, 128, kk); }
#define STG_U1(bufv, kk) { STG_A(bufv, 64, kk);  STG_A(bufv, 192, kk); }
#define STG_U2(bufv, kk) { STG_B(bufv, 0, kk);   STG_B(bufv, 128, kk); }
#define STG_U3(bufv, kk) { STG_B(bufv, 32, kk);  STG_B(bufv, 160, kk); }

#define LDS_A(dst, qmv, bufv) do { \
    const u16* p_ = ABUF(bufv); \
    _Pragma("unroll") for (int mt = 0; mt < 4; mt++) { \
      int row_ = wm*128 + (qmv)*64 + mt*16 + fm; \
      _Pragma("unroll") for (int ks = 0; ks < 2; ks++) \
        dst[mt][ks] = *(const short8*)(p_ + row_*64 + (((ks*4 + fq) ^ (fm & 7)) * 8)); \
    } } while (0)
#define LDS_Bv(dst, qnv, bufv) do { \
    const u16* p_ = BBUF(bufv); \
    _Pragma("unroll") for (int nt = 0; nt < 2; nt++) { \
      int row_ = wn*64 + (qnv)*32 + nt*16 + fm; \
      _Pragma("unroll") for (int ks = 0; ks < 2; ks++) \
        dst[nt][ks] = *(const short8*)(p_ + row_*64 + (((ks*4 + fq) ^ (fm & 7)) * 8)); \
    } } while (0)

#define MMQ(qmv, qnv, Bv) do { \
    __builtin_amdgcn_s_setprio(1); \
    _Pragma("unroll") for (int mt = 0; mt < 4; mt++) \
    _Pragma("unroll") for (int nt = 0; nt < 2; nt++) \
    _Pragma("unroll") for (int ks = 0; ks < 2; ks++) \
      acc[(qmv)*4 + mt][(qnv)*2 + nt] = __builtin_amdgcn_mfma_f32_16x16x32_bf16( \
          a[mt][ks], Bv[nt][ks], acc[(qmv)*4 + mt][(qnv)*2 + nt], 0, 0, 0); \
    __builtin_amdgcn_s_setprio(0); } while (0)

// One K-tile: 4 phases, 2 barriers each. k1 = k of tile t+1 (into buf^1),
// k2 = k of tile t+2 (into bufv). S* gate tail stages; W* are the counted waits.
#define GT(bufv, k1, k2, S01, S23, W0, W1, W3) do { \
    /* P0 */ \
    LDS_A(a, 0, bufv); \
    LDS_Bv(b0r, 0, bufv); \
    if (S01) STG_U3((bufv)^1, k1); \
    BARRIER; \
    MMQ(0, 0, b0r); \
    W0; \
    BARRIER; \
    /* P1 */ \
    LDS_Bv(b1r, 1, bufv); \
    if (S01) STG_U1((bufv)^1, k1); \
    BARRIER; \
    MMQ(0, 1, b1r); \
    W1; \
    BARRIER; \
    /* P2 */ \
    LDS_A(a, 1, bufv); \
    if (S23) STG_U0(bufv, k2); \
    BARRIER; \
    MMQ(1, 1, b1r); \
    BARRIER; \
    /* P3 */ \
    if (S23) STG_U2(bufv, k2); \
    BARRIER; \
    MMQ(1, 0, b0r); \
    W3; \
    BARRIER; \
  } while (0)

__global__ __launch_bounds__(512, 2) void k_gemm1(const u16* __restrict__ A,
                                                  const u16* __restrict__ Bw,
                                                  const float* __restrict__ bias,
                                                  u16* __restrict__ qkv,
                                                  u16* __restrict__ cat) {
  const int K = HDIM;
  // XCD-bijective swizzle: 896 blocks, 896 % 8 == 0 -> 112 per XCD
  int orig = blockIdx.x;
  int bid = (orig & 7) * 112 + (orig >> 3);
  int bm = bid & 15, bn = bid >> 4;      // bm fastest within an XCD chunk
  int t = threadIdx.x, wave = t >> 6, lane = t & 63;
  int wm = wave >> 2, wn = wave & 3;     // 2x4 wave grid, wave tile 128x64
  int fm = lane & 15, fq = lane >> 4;
  int lr = lane >> 3, lg = lane & 7;     // staging: row-in-band / granule
  int sg = lg ^ lr;                      // pre-swizzled global source granule

  __shared__ u16 S[65536];               // 128 KiB: A dbuf + B dbuf

  const u16* Ab = A + (size_t)bm * 256 * K;
  const u16* Bb = Bw + (size_t)bn * 256 * K;

  const f32x4 fzero = {0.f, 0.f, 0.f, 0.f};
  f32x4 acc[8][4];
#pragma unroll
  for (int i = 0; i < 8; i++)
#pragma unroll
    for (int j2 = 0; j2 < 4; j2++) acc[i][j2] = fzero;
  short8 a[4][2], b0r[2][2], b1r[2][2];

  // prologue: tile0 (U0,U2,U3,U1 -> buf0) + U0_1,U2_1 (-> buf1), 12 loads;
  // vmcnt(8) drains tile0's U0,U2 (needed by P0_0 reads). Invariant holds at P0_0.
  STG_U0(0, 0); STG_U2(0, 0); STG_U3(0, 0); STG_U1(0, 0);
  STG_U0(1, 64); STG_U2(1, 64);
  WAITVM(8);
  BARRIER;

  for (int t2 = 0; t2 < 15; ++t2) {      // tiles 0..29
    int k0 = t2 * 128;
    GT(0, k0+64,  k0+128, 1, 1, WAITVM(8), WAITVM(8), WAITVM(8));
    GT(1, k0+128, k0+192, 1, 1, WAITVM(8), WAITVM(8), WAITVM(8));
  }
  // tile 30: stage U3_31/U1_31 only; P3 drains U0_31,U2_31 with vmcnt(4)
  GT(0, 31*64, 0, 1, 0, WAITVM(8), WAITVM(8), WAITVM(4));
  // tile 31: no stages; drain remaining U3_31 (vmcnt(2)) then U1_31 (vmcnt(0))
  GT(1, 0, 0, 0, 0, WAITVM(2), WAITVM(0), ((void)0));

  // ---- epilogue: bias (+gelu for mlp), LDS restage, coalesced 16B stores ----
  bool ismlp = (bn >= 24);               // 3H = 6144 = 24*256, uniform per block
  const int EP = 264;                    // padded pitch
  u16* Sep = S;                          // reuse LDS (33792 u16 <= 65536)
#pragma unroll
  for (int half = 0; half < 2; half++) {
    BARRIER;
    if (wm == half) {
#pragma unroll
      for (int j = 0; j < 4; j++) {
        int col_l = wn*64 + j*16 + fm;
        float bv = bias[bn*256 + col_l];
#pragma unroll
        for (int i = 0; i < 8; i++) {
#pragma unroll
          for (int rr = 0; rr < 4; rr++) {
            float v = acc[i][j][rr] + bv;
            if (ismlp) v = gelu_f(v);
            Sep[(i*16 + fq*4 + rr)*EP + col_l] = f2bf(v);
          }
        }
      }
    }
    __syncthreads();
    int cg = (t & 31) * 8;
    int r0 = t >> 5;
#pragma unroll
    for (int p = 0; p < 8; p++) {
      int r_l = p*16 + r0;
      short8 v = *(const short8*)&Sep[r_l*EP + cg];
      int row_g = bm*256 + half*128 + r_l;
      if (!ismlp)
        *(short8*)(qkv + (size_t)row_g*(3*HDIM) + bn*256 + cg) = v;
      else
        *(short8*)(cat + (size_t)row_g*NC + HDIM + (bn-24)*256 + cg) = v;
    }
    __syncthreads();
  }
}

// ---------------- GEMM2: out = x + gate*(cat @ W2^T + b2) ----------------
__global__ __launch_bounds__(256, 2) void k_gemm2(const u16* __restrict__ A,
                                                  const u16* __restrict__ Bw,
                                                  const float* __restrict__ bias,
                                                  const float* __restrict__ xres,
                                                  const float* __restrict__ modv,
                                                  float* __restrict__ out) {
  const int K = NC;
  int bid = blockIdx.x;
  int bm = bid & 31, bn = bid >> 5;     // bm fastest
  int t = threadIdx.x, wave = t >> 6, lane = t & 63;
  int wm = wave >> 1, wn = wave & 1;
  __shared__ u16 As[2*128*32];
  __shared__ u16 Bs[2*128*32];
  const f32x4 fzero = {0.f, 0.f, 0.f, 0.f};
  f32x4 acc[4][4];
#pragma unroll
  for (int i = 0; i < 4; i++)
#pragma unroll
    for (int j2 = 0; j2 < 4; j2++) acc[i][j2] = fzero;
  const u16* Ab = A + (size_t)bm * 128 * K;
  const u16* Bb = Bw + (size_t)bn * 128 * K;
  int r4 = lane >> 2, c4 = lane & 3;
  int fm = lane & 15, fk = (lane >> 4) * 8;
  for (int k0 = 0; k0 < K; k0 += 64) {
#pragma unroll
    for (int i = 0; i < 2; i++) {
      int row = wave*32 + i*16;
      const u16* ar = Ab + (size_t)(row + r4)*K + k0 + c4*8;
      const u16* br = Bb + (size_t)(row + r4)*K + k0 + c4*8;
      ASYNC16(ar,      &As[row*32]);
      ASYNC16(ar + 32, &As[4096 + row*32]);
      ASYNC16(br,      &Bs[row*32]);
      ASYNC16(br + 32, &Bs[4096 + row*32]);
    }
    __syncthreads();
#pragma unroll
    for (int p = 0; p < 2; p++) {
      const u16* Ap = &As[p*4096];
      const u16* Bp = &Bs[p*4096];
      short8 af[4], bfr[4];
#pragma unroll
      for (int mt = 0; mt < 4; mt++)
        af[mt] = *(const short8*)&Ap[(wm*64 + mt*16 + fm)*32 + fk];
#pragma unroll
      for (int nt = 0; nt < 4; nt++)
        bfr[nt] = *(const short8*)&Bp[(wn*64 + nt*16 + fm)*32 + fk];
#pragma unroll
      for (int mt = 0; mt < 4; mt++)
#pragma unroll
        for (int nt = 0; nt < 4; nt++)
          acc[mt][nt] = __builtin_amdgcn_mfma_f32_16x16x32_bf16(af[mt], bfr[nt], acc[mt][nt], 0, 0, 0);
    }
    __syncthreads();
  }
  int rbase = bm*128 + wm*64;
  int cbase = bn*128 + wn*64;
  int b = (bm*128) >> 11;
#pragma unroll
  for (int nt = 0; nt < 4; nt++) {
    int col = cbase + nt*16 + fm;
    float bv = bias[col];
    float g = modv[b*(3*HDIM) + 2*HDIM + col];
#pragma unroll
    for (int mt = 0; mt < 4; mt++) {
#pragma unroll
      for (int rr = 0; rr < 4; rr++) {
        int row = rbase + mt*16 + (lane>>4)*4 + rr;
        size_t idx = (size_t)row*HDIM + col;
        out[idx] = xres[idx] + g * (acc[mt][nt][rr] + bv);
      }
    }
  }
}

// ---------------- q,k: rmsnorm + rope -> Q,K (b,h,l,d) bf16 ----------------
__global__ __launch_bounds__(256) void k_qk(const u16* __restrict__ qkv,
                                            const float* __restrict__ pe,
                                            const float* __restrict__ q_scale,
                                            const float* __restrict__ k_scale,
                                            u16* __restrict__ Q, u16* __restrict__ Ko) {
  int bid = blockIdx.x;                  // b*L + l
  int l = bid & (LSEQ-1);
  int b = bid >> 11;
  int t = threadIdx.x;
  int h = t >> 4;
  int dc = (t & 15) * 8;
  const u16* base = qkv + (size_t)bid * (3*HDIM);
  short8 q8 = *(const short8*)(base + h*DHEAD + dc);
  short8 k8 = *(const short8*)(base + HDIM + h*DHEAD + dc);
  float qf[8], kf[8];
  float sq = 0.f, sk = 0.f;
#pragma unroll
  for (int i = 0; i < 8; i++) {
    qf[i] = bf2f((u16)q8[i]); kf[i] = bf2f((u16)k8[i]);
    sq += qf[i]*qf[i]; sk += kf[i]*kf[i];
  }
#pragma unroll
  for (int m = 1; m < 16; m <<= 1) { sq += __shfl_xor(sq, m, 64); sk += __shfl_xor(sk, m, 64); }
  float rq = rsqrtf(sq * (1.f/DHEAD) + 1e-6f);
  float rk = rsqrtf(sk * (1.f/DHEAD) + 1e-6f);
  float4 qs0 = *(const float4*)(q_scale + dc), qs1 = *(const float4*)(q_scale + dc + 4);
  float4 ks0 = *(const float4*)(k_scale + dc), ks1 = *(const float4*)(k_scale + dc + 4);
  float qsc[8] = {qs0.x,qs0.y,qs0.z,qs0.w,qs1.x,qs1.y,qs1.z,qs1.w};
  float ksc[8] = {ks0.x,ks0.y,ks0.z,ks0.w,ks1.x,ks1.y,ks1.z,ks1.w};
  float qn[8], kn[8];
#pragma unroll
  for (int i = 0; i < 8; i++) { qn[i] = qf[i]*rq*qsc[i]; kn[i] = kf[i]*rk*ksc[i]; }
  const float4* pe4 = (const float4*)pe + ((size_t)bid*64 + (dc >> 1));
  short8 qo, ko;
#pragma unroll
  for (int pi = 0; pi < 4; pi++) {
    float4 pp = pe4[pi];
    float q0 = pp.x*qn[2*pi] + pp.y*qn[2*pi+1];
    float q1 = pp.z*qn[2*pi] + pp.w*qn[2*pi+1];
    float k0 = pp.x*kn[2*pi] + pp.y*kn[2*pi+1];
    float k1 = pp.z*kn[2*pi] + pp.w*kn[2*pi+1];
    qo[2*pi] = (short)f2bf(q0); qo[2*pi+1] = (short)f2bf(q1);
    ko[2*pi] = (short)f2bf(k0); ko[2*pi+1] = (short)f2bf(k1);
  }
  size_t oidx = (((size_t)(b*NHEAD + h))*LSEQ + l)*DHEAD + dc;
  *(short8*)(Q + oidx) = qo;
  *(short8*)(Ko + oidx) = ko;
}

// ---------------- V transpose: qkv v-part -> Vt (b,h,d,l) bf16 ----------------
__global__ __launch_bounds__(256) void k_vt(const u16* __restrict__ qkv, u16* __restrict__ Vt) {
  int bid = blockIdx.x;
  int lt = bid & 31, h = (bid >> 5) & 15, b = bid >> 9;
  __shared__ u16 tile[64][132];
  int t = threadIdx.x;
#pragma unroll
  for (int it = 0; it < 8; it++) {
    int idx = it*1024 + t*4;
    int li = idx >> 7, di = idx & 127;
    const u16* src = qkv + ((size_t)(b*LSEQ + lt*64 + li))*(3*HDIM) + 2*HDIM + h*DHEAD + di;
    ushort4 v = *(const ushort4*)src;
    *(ushort4*)&tile[li][di] = v;
  }
  __syncthreads();
  u16* dst = Vt + ((size_t)(b*NHEAD + h))*DHEAD*LSEQ + lt*64;
#pragma unroll
  for (int it = 0; it < 32; it++) {
    int idx = it*256 + t;
    int lo = idx & 63, dd = idx >> 6;
    dst[(size_t)dd*LSEQ + lo] = tile[lo][dd];
  }
}

// ---------------- flash attention: no-max softmax (rmsnorm bounds logits) ----------------
// |q|=|k|=sqrt(128)*O(1) after rmsnorm => |logit| <~ 34; exp2 range-safe in fp32.
#define SC2 0.12753329583f   // (1/sqrt(128)) * log2(e)
__global__ __launch_bounds__(256, 2) void k_attn(const u16* __restrict__ Q,
                                                 const u16* __restrict__ Kc,
                                                 const u16* __restrict__ Vt,
                                                 u16* __restrict__ cat) {
  __shared__ u16 Ks[2*64*128];   // 32 KB dbuf
  __shared__ u16 Vs[2*128*64];   // 32 KB dbuf
  __shared__ u16 Ps[64*88];      // per-wave private rows
  int bid = blockIdx.x;
  int bh = bid & 31, qt = bid >> 5;
  int h = bh & 15, b = bh >> 4;
  int t = threadIdx.x, wave = t >> 6, lane = t & 63;
  int fm = lane & 15, fq = lane >> 4;
  int r8 = lane >> 3, c8 = lane & 7;
  const u16* Qg = Q  + (((size_t)(b*NHEAD + h))*LSEQ + qt*64) * DHEAD;
  const u16* Kg = Kc + ((size_t)(b*NHEAD + h))*LSEQ * DHEAD;
  const u16* Vg = Vt + ((size_t)(b*NHEAD + h))*DHEAD*LSEQ;
  short8 aq[4];
#pragma unroll
  for (int ks = 0; ks < 4; ks++)
    aq[ks] = *(const short8*)(Qg + (size_t)(wave*16 + fm)*DHEAD + ks*32 + fq*8);
#pragma unroll
  for (int i = 0; i < 4; i++) {
    int row = wave*16 + i*4;
    ASYNC16(Kg + (size_t)(row + fq)*DHEAD + fm*8, &Ks[row*DHEAD]);
    int vrow = wave*32 + i*8;
    ASYNC16(Vg + (size_t)(vrow + r8)*LSEQ + c8*8, &Vs[vrow*64]);
  }
  const f32x4 fzero = {0.f, 0.f, 0.f, 0.f};
  f32x4 o[8];
#pragma unroll
  for (int i = 0; i < 8; i++) o[i] = fzero;
  float lsum[4] = {0.f, 0.f, 0.f, 0.f};
  for (int kt = 0; kt < 32; kt++) {
    int cur = kt & 1;
    __syncthreads();   // drains prev-iter staging (issued a full iter ago)
    if (kt < 31) {
      int off = (cur ^ 1) * 8192;
      const u16* Kt_ = Kg + (size_t)(kt+1)*64*DHEAD;
      const u16* Vt_ = Vg + (kt+1)*64;
#pragma unroll
      for (int i = 0; i < 4; i++) {
        int row = wave*16 + i*4;
        ASYNC16(Kt_ + (size_t)(row + fq)*DHEAD + fm*8, &Ks[off + row*DHEAD]);
        int vrow = wave*32 + i*8;
        ASYNC16(Vt_ + (size_t)(vrow + r8)*LSEQ + c8*8, &Vs[off + vrow*64]);
      }
    }
    const u16* Kb = &Ks[cur*8192];
    const u16* Vb = &Vs[cur*8192];
    f32x4 s[4];
#pragma unroll
    for (int nt = 0; nt < 4; nt++) s[nt] = fzero;
#pragma unroll
    for (int ks = 0; ks < 4; ks++) {
#pragma unroll
      for (int nt = 0; nt < 4; nt++) {
        short8 bk = *(const short8*)&Kb[(nt*16 + fm)*DHEAD + ks*32 + fq*8];
        s[nt] = __builtin_amdgcn_mfma_f32_16x16x32_bf16(aq[ks], bk, s[nt], 0, 0, 0);
      }
    }
    // p = 2^(s*SC2); accumulate per-lane row sums, no max / no rescale
#pragma unroll
    for (int nt = 0; nt < 4; nt++)
#pragma unroll
      for (int r = 0; r < 4; r++) {
        float p = exp2f(s[nt][r] * SC2);
        s[nt][r] = p;
        lsum[r] += p;
      }
#pragma unroll
    for (int nt = 0; nt < 4; nt++)
#pragma unroll
      for (int r = 0; r < 4; r++)
        Ps[(wave*16 + fq*4 + r)*88 + nt*16 + fm] = f2bf_trunc(s[nt][r]);
    asm volatile("s_waitcnt lgkmcnt(0)" ::: "memory");
#pragma unroll
    for (int ks2 = 0; ks2 < 2; ks2++) {
      short8 ap = *(const short8*)&Ps[(wave*16 + fm)*88 + ks2*32 + fq*8];
#pragma unroll
      for (int nt = 0; nt < 8; nt++) {
        short8 bv = *(const short8*)&Vb[(nt*16 + fm)*64 + ks2*32 + fq*8];
        o[nt] = __builtin_amdgcn_mfma_f32_16x16x32_bf16(ap, bv, o[nt], 0, 0, 0);
      }
    }
  }
  // single final reduction of row sums over the 16 column-lanes
#pragma unroll
  for (int r = 0; r < 4; r++) {
#pragma unroll
    for (int o2 = 8; o2 >= 1; o2 >>= 1) lsum[r] += __shfl_xor(lsum[r], o2, 64);
  }
#pragma unroll
  for (int nt = 0; nt < 8; nt++) {
#pragma unroll
    for (int r = 0; r < 4; r++) {
      int l = qt*64 + wave*16 + fq*4 + r;
      int d = nt*16 + fm;
      float v = o[nt][r] / lsum[r];
      cat[((size_t)(b*LSEQ + l))*NC + h*DHEAD + d] = f2bf(v);
    }
  }
}

// ---------------- launch ----------------
extern "C" void kernel_launch(void* const* d_in, const int* in_sizes, int n_in,
                              void* d_out, int out_size, void* d_ws, size_t ws_size,
                              hipStream_t stream) {
  const float* x       = (const float*)d_in[0];
  const float* vec     = (const float*)d_in[1];
  const float* pe      = (const float*)d_in[2];
  const float* mod_w   = (const float*)d_in[3];
  const float* mod_b   = (const float*)d_in[4];
  const float* lin1_w  = (const float*)d_in[5];
  const float* lin1_b  = (const float*)d_in[6];
  const float* lin2_w  = (const float*)d_in[7];
  const float* lin2_b  = (const float*)d_in[8];
  const float* q_scale = (const float*)d_in[9];
  const float* k_scale = (const float*)d_in[10];
  char* ws = (char*)d_ws;

  // workspace layout, high-water ~210 MB
  float* modv = (float*)(ws + 0);                 //  48 KB
  u16* xmod  = (u16*)(ws + 65536ULL);             //  16.8 MB
  u16* qkv   = (u16*)(ws + 16842752ULL);          //  50.3 MB (dead after qk/vt)
  u16* w2    = (u16*)(ws + 16842752ULL);          //  aliases qkv (written after qk/vt)
  u16* cat   = (u16*)(ws + 67174400ULL);          //  83.9 MB
  u16* w1    = (u16*)(ws + 151060480ULL);         //  58.7 MB (dead after GEMM1)
  u16* Qb    = (u16*)(ws + 151060480ULL);         //  aliases w1
  u16* Kb    = (u16*)(ws + 167837696ULL);
  u16* Vtb   = (u16*)(ws + 184614912ULL);         //  end at ~201.4 MB

  k_mod<<<dim3(3*HDIM), dim3(256), 0, stream>>>(vec, mod_w, mod_b, modv);
  k_cvt<<<dim3(4096), dim3(256), 0, stream>>>((const float4*)lin1_w, (ushort4*)w1, (N1*HDIM)/4);
  k_ln<<<dim3(4096), dim3(256), 0, stream>>>(x, modv, xmod);
  k_gemm1<<<dim3(896), dim3(512), 0, stream>>>(xmod, w1, lin1_b, qkv, cat);
  k_qk<<<dim3(4096), dim3(256), 0, stream>>>(qkv, pe, q_scale, k_scale, Qb, Kb);
  k_vt<<<dim3(1024), dim3(256), 0, stream>>>(qkv, Vtb);
  k_cvt<<<dim3(4096), dim3(256), 0, stream>>>((const float4*)lin2_w, (ushort4*)w2, (HDIM*NC)/4);
  k_attn<<<dim3(1024), dim3(256), 0, stream>>>(Qb, Kb, Vtb, cat);
  k_gemm2<<<dim3(32*16), dim3(256), 0, stream>>>(cat, w2, lin2_b, x, modv, (float*)d_out);
}